// Round 1
// 427.027 us; speedup vs baseline: 1.0044x; 1.0044x over previous
//
#include <hip/hip_runtime.h>

// Problem constants (from reference): img (N,C,H,W) fp32, disp (N,1,H,W) fp32.
#define N_ 4
#define C_ 32
#define H_ 384
#define W_ 1280
#define WP_ (W_ + 8)   // padded LDS row stride (floats); 16B-aligned (5152 B)

// One block per (n,h) row. 320 threads = 5 waves; each thread owns a 4-pixel
// quad (320*4 = 1280 = W). Per channel:
//   1. async global->LDS stage of the next channel's row (coalesced,
//      global_load_lds dwordx4: wave w stages bytes into [16 + w*1024, ...))
//   2. gather current channel from LDS (bilinear taps), blend, float4 store
//   3. __syncthreads() — drains vmcnt (next row staged) + guards LDS reuse
//
// Zeros-padding is materialized IN LDS: image element w lives at LDS index
// w+4; guard zeros at indices [0..3] and [W+4..W+7] (written once, never
// overwritten by staging). Reference semantics: x clipped to [0, W+1] into a
// zero-padded row; taps are ALWAYS (x0, x0+1) — when x is integral dx=0 kills
// the second term, so no ceil() and no per-tap masks are needed. Each pixel's
// gather is an unconditional adjacent pair -> one ds_read2_b32 + mul + fma.
__device__ __forceinline__ void stage16(const float* g, float* l) {
    __builtin_amdgcn_global_load_lds(
        (const __attribute__((address_space(1))) void*)g,
        (__attribute__((address_space(3))) void*)l, 16, 0, 0);
}

__global__ __launch_bounds__(320) void warp1d_kernel(
    const float* __restrict__ img,
    const float* __restrict__ disp,
    float* __restrict__ out)
{
    __shared__ float buf[2][WP_];

    const int tid  = threadIdx.x;
    const int nh   = blockIdx.x;          // n*H + h
    const int w0   = tid * 4;
    const int lane = tid & 63;
    const int wave = tid >> 6;
    // this wave's staging slice within the row (floats, relative to pad base)
    const int chunk = wave * 256 + lane * 4;   // 64 lanes * 16B = 1 KiB / wave

    // zero the guard columns of both buffers once (staging never touches them)
    if (tid < 16) {
        const int b = tid >> 3;
        const int z = tid & 7;
        buf[b][(z < 4) ? z : (W_ + z)] = 0.0f;   // [0..3] and [W+4..W+7]
    }

    // ---- per-row warp coordinates (computed once, reused for all C) ----
    const float4 d4 = *(const float4*)(disp + (long)nh * W_ + w0);
    const float dv[4] = {d4.x, d4.y, d4.z, d4.w};

    int   ix[4];            // LDS index of left tap (already +4 pad-shifted)
    float fx[4], wa[4];     // dx and (1-dx)
#pragma unroll
    for (int j = 0; j < 4; ++j) {
        float x = (float)(w0 + j) - dv[j];
        x = fminf(fmaxf(x, -1.0f), (float)W_) + 1.0f;   // x in [0, W+1]
        const float xf = floorf(x);
        fx[j] = x - xf;
        wa[j] = 1.0f - fx[j];
        // padded coord x0 = xf; unpadded tap a = x0-1 in [-1, W];
        // LDS index = a + 4 = x0 + 3. Right tap ix+1 <= W+5 (guard zero).
        ix[j] = (int)xf + 3;
    }

    const int  n = nh / H_;
    const int  h = nh % H_;
    const long rowbase = ((long)n * C_ * H_ + h) * W_;   // c=0 row offset
    const float* gsrc = img + rowbase + chunk;           // staging src, c=0
    float*       gdst = out + rowbase + w0;              // output dst,  c=0

    // prefetch channel 0 into buf[0] (dest 16B-aligned: pad offset = 16 B)
    stage16(gsrc, &buf[0][4 + wave * 256]);
    gsrc += (long)H_ * W_;
    __syncthreads();   // drains vmcnt -> buf[0] ready; guard zeros visible

#pragma unroll 2
    for (int c = 0; c < C_; ++c) {
        if (c + 1 < C_) {
            stage16(gsrc, &buf[(c + 1) & 1][4 + wave * 256]);
            gsrc += (long)H_ * W_;
        }
        const float* __restrict__ r = buf[c & 1];
        float4 o;
        float* op = (float*)&o;
#pragma unroll
        for (int j = 0; j < 4; ++j) {
            const float v0 = r[ix[j]];        // adjacent pair ->
            const float v1 = r[ix[j] + 1];    //   ds_read2_b32
            op[j] = fmaf(fx[j], v1, wa[j] * v0);
        }
        *(float4*)gdst = o;
        gdst += (long)H_ * W_;
        // one barrier: (a) everyone done reading buf[c&1] before it is
        // re-staged at iter c+1, (b) drains vmcnt so buf[(c+1)&1] is ready.
        __syncthreads();
    }
}

extern "C" void kernel_launch(void* const* d_in, const int* in_sizes, int n_in,
                              void* d_out, int out_size, void* d_ws, size_t ws_size,
                              hipStream_t stream) {
    const float* img  = (const float*)d_in[0];
    const float* disp = (const float*)d_in[1];
    float* out = (float*)d_out;

    constexpr int grid  = N_ * H_;   // 1536 blocks, one per image row
    constexpr int block = 320;       // 5 waves; 4 pixels/thread

    warp1d_kernel<<<grid, block, 0, stream>>>(img, disp, out);
}

// Round 2
// 415.242 us; speedup vs baseline: 1.0329x; 1.0284x over previous
//
#include <hip/hip_runtime.h>

// Problem constants (from reference): img (N,C,H,W) fp32, disp (N,1,H,W) fp32.
#define N_ 4
#define C_ 32
#define H_ 384
#define W_ 1280
#define WP_ (W_ + 8)   // padded LDS row stride (floats); 16B-aligned (5152 B)

// One block per (n,h) row. 320 threads = 5 waves; thread owns a 4-pixel quad.
//
// R2: counted-vmcnt 2-deep channel pipeline (T3/T4). 3 LDS row buffers;
// channels c and c+1 staged in the prologue; iteration c stages c+2 and waits
// only s_waitcnt vmcnt(N) for its OWN stage of channel c (issued 2 iters ago)
// — never vmcnt(0) — then one raw s_barrier makes all waves' stages visible.
// Buffer-reuse safety: iter c stages c+2 into buf[(c+2)%3] == buf[(c-1)%3],
// whose readers all passed barrier_c before the stage is issued.
//
// vmcnt counting (stores count toward vmcnt on CDNA): at iter c the wave needs
// stage_c complete. Guaranteed-younger VMEM ops: stage_{c+1} plus the stores
// of iters c-2..c-1 whose order vs stage_c/stage_{c+1} the compiler may
// permute — so we use the permutation-robust lower bound: vmcnt(1) at c=0,
// vmcnt(2) for c=1..30, vmcnt(1) at c=31. Over-waits at most one 2-iter-old
// store (long retired). "memory"-clobber asm fences pin memory-op order at
// phase edges so LDS reads can't hoist above the barrier.
//
// Zeros-padding lives IN LDS: element w at index w+4; guard zeros [0..3] and
// [W+4..W+7] written once. Taps are always (x0, x0+1) -> ds_read2_b32 + fma.
__device__ __forceinline__ void stage16(const float* g, float* l) {
    __builtin_amdgcn_global_load_lds(
        (const __attribute__((address_space(1))) void*)g,
        (__attribute__((address_space(3))) void*)l, 16, 0, 0);
}

__global__ __launch_bounds__(320) void warp1d_kernel(
    const float* __restrict__ img,
    const float* __restrict__ disp,
    float* __restrict__ out)
{
    __shared__ float buf[3][WP_];

    const int tid  = threadIdx.x;
    const int nh   = blockIdx.x;          // n*H + h
    const int w0   = tid * 4;
    const int lane = tid & 63;
    const int wave = tid >> 6;
    const int chunk = wave * 256 + lane * 4;   // 64 lanes * 16B = 1 KiB / wave

    // zero the guard columns of all three buffers once
    if (tid < 24) {
        const int b = tid >> 3;
        const int z = tid & 7;
        buf[b][(z < 4) ? z : (W_ + z)] = 0.0f;   // [0..3] and [W+4..W+7]
    }

    // ---- per-row warp coordinates (computed once, reused for all C) ----
    const float4 d4 = *(const float4*)(disp + (long)nh * W_ + w0);
    const float dv[4] = {d4.x, d4.y, d4.z, d4.w};

    int   ix[4];            // LDS index of left tap (already +4 pad-shifted)
    float fx[4], wa[4];     // dx and (1-dx)
#pragma unroll
    for (int j = 0; j < 4; ++j) {
        float x = (float)(w0 + j) - dv[j];
        x = fminf(fmaxf(x, -1.0f), (float)W_) + 1.0f;   // x in [0, W+1]
        const float xf = floorf(x);
        fx[j] = x - xf;
        wa[j] = 1.0f - fx[j];
        ix[j] = (int)xf + 3;   // unpadded tap a = x0-1 in [-1,W]; LDS idx a+4
    }

    const int  n = nh / H_;
    const int  h = nh % H_;
    const long HW = (long)H_ * W_;
    const long rowbase = ((long)n * C_ * H_ + h) * W_;   // c=0 row offset

#define STAGE_CH(c) \
    stage16(img + rowbase + (long)(c) * HW + chunk, &buf[(c) % 3][4 + wave * 256])

    STAGE_CH(0);
    STAGE_CH(1);
    asm volatile("s_waitcnt lgkmcnt(0)" ::: "memory");   // guard zeros landed

#define BODY(c, VM) do {                                                      \
    asm volatile("s_waitcnt vmcnt(" #VM ")" ::: "memory");                    \
    __builtin_amdgcn_s_barrier();                                             \
    asm volatile("" ::: "memory");   /* no LDS read hoists above barrier */   \
    if ((c) + 2 < C_) { STAGE_CH((c) + 2); }                                  \
    asm volatile("" ::: "memory");   /* pin stage-issue before gather/store*/ \
    const float* __restrict__ r = buf[(c) % 3];                               \
    float4 o; float* op = (float*)&o;                                         \
    op[0] = fmaf(fx[0], r[ix[0] + 1], wa[0] * r[ix[0]]);                      \
    op[1] = fmaf(fx[1], r[ix[1] + 1], wa[1] * r[ix[1]]);                      \
    op[2] = fmaf(fx[2], r[ix[2] + 1], wa[2] * r[ix[2]]);                      \
    op[3] = fmaf(fx[3], r[ix[3] + 1], wa[3] * r[ix[3]]);                      \
    *(float4*)(out + rowbase + (long)(c) * HW + w0) = o;                      \
} while (0)

    BODY(0, 1);
    BODY(1, 2);
#pragma unroll
    for (int c = 2; c <= 30; ++c) BODY(c, 2);
    BODY(31, 1);

#undef BODY
#undef STAGE_CH
}

extern "C" void kernel_launch(void* const* d_in, const int* in_sizes, int n_in,
                              void* d_out, int out_size, void* d_ws, size_t ws_size,
                              hipStream_t stream) {
    const float* img  = (const float*)d_in[0];
    const float* disp = (const float*)d_in[1];
    float* out = (float*)d_out;

    constexpr int grid  = N_ * H_;   // 1536 blocks, one per image row
    constexpr int block = 320;       // 5 waves; 4 pixels/thread

    warp1d_kernel<<<grid, block, 0, stream>>>(img, disp, out);
}